// Round 11
// baseline (235.610 us; speedup 1.0000x reference)
//
#include <hip/hip_runtime.h>
#include <hip/hip_bf16.h>

#define NN 100000
#define NE 1600000
#define D  128
#define NPAD 100352           // 392 * 256 = 196 * 512
#define NBLK 782              // ceil(NN / 128)
#define CAP  64               // max in-degree bucket (Poisson(16): P(>=64)~8e-20)

// coarse partition params
#define BSH    9              // bucket = dest >> 9  (512 nodes/bucket)
#define NB_C   196            // NPAD >> 9
#define CAPB   9216           // bucket arena capacity (mean 8163, +11 sigma)
#define PCHUNK 2048           // edges per partition block (256 thr, proven r5 cfg)
#define PEPT   8              // edges per thread
#define NPART  782            // ceil(NE / PCHUNK)
#define FUSED_BLOCKS (NPART + NBLK)   // 1564: even = part, odd = gemm

typedef __attribute__((ext_vector_type(8))) short short8;
typedef __attribute__((ext_vector_type(4))) float floatx4;
typedef __attribute__((ext_vector_type(4))) unsigned int uintx4;

__device__ __forceinline__ unsigned short f2b(float f) {
    __hip_bfloat16 h = __float2bfloat16(f);   // RNE
    return *(unsigned short*)&h;
}

// scaled unpack-accumulate: a[j] += d * bf16_unpack(v)[j]  (8 FMAs)
__device__ __forceinline__ void acc8f(float (&a)[8], uintx4 v, float d) {
    a[0] += d * __uint_as_float(v.x << 16);
    a[1] += d * __uint_as_float(v.x & 0xFFFF0000u);
    a[2] += d * __uint_as_float(v.y << 16);
    a[3] += d * __uint_as_float(v.y & 0xFFFF0000u);
    a[4] += d * __uint_as_float(v.z << 16);
    a[5] += d * __uint_as_float(v.z & 0xFFFF0000u);
    a[6] += d * __uint_as_float(v.w << 16);
    a[7] += d * __uint_as_float(v.w & 0xFFFF0000u);
}

// LDS tile swizzle for [128 rows][128 bf16] (256 B rows): XOR 16 B-granule
// index with (row&7) -- G4 pattern. In ushort units: col ^ ((row&7)<<3).
__device__ __forceinline__ int swz(int row, int col_us) {
    return row * 128 + (col_us ^ ((row & 7) << 3));
}

// ------------------- FUSED: partition (even blocks) + GEMM (odd blocks) ----
// The GEMM no longer applies dinv (moved to k_agg as a per-source scale:
// out[c] = dinv[c]*sum_s dinv[s]*xw[s] + bias, self-loop = source c), so it
// depends only on x,w and is INDEPENDENT of the edge pipeline -> both roles
// run concurrently, overlapping part's LDS-atomic/scatter phase with gemm's
// HBM-stream/MFMA phase. edgesP now aliases d_out (dead until k_agg), NOT
// yw (live here).
__global__ __launch_bounds__(256, 2) void k_fused(const float* __restrict__ x,
                                                  const float* __restrict__ w,
                                                  const int* __restrict__ row,
                                                  const int* __restrict__ col,
                                                  int* __restrict__ bcnt,
                                                  unsigned int* __restrict__ edgesP,
                                                  unsigned short* __restrict__ yw) {
    __shared__ __align__(16) unsigned short smem[2 * 128 * 128];   // 64 KB
    int tid = threadIdx.x;
    int pid = blockIdx.x >> 1;

    if ((blockIdx.x & 1) == 0) {
        // ---------------- partition role (r5-proven 2048@256 shape) --------
        int* cur   = (int*)smem;
        int* basep = cur + NB_C;
        size_t e0 = (size_t)pid * PCHUNK;

        for (int i = tid; i < NB_C; i += 256) cur[i] = 0;
        __syncthreads();

        unsigned int val[PEPT];
        int bk[PEPT], rk[PEPT];
#pragma unroll
        for (int i = 0; i < PEPT; ++i) {
            size_t e = e0 + i * 256 + tid;
            bk[i] = -1;
            if (e < NE) {
                int r = row[e], c = col[e];
                if (r != c) {                  // existing self-loops weight 0
                    bk[i]  = c >> BSH;
                    val[i] = (unsigned)r | ((unsigned)(c & 511) << 17);
                    rk[i]  = atomicAdd(&cur[bk[i]], 1);   // LDS atomic
                }
            }
        }
        __syncthreads();

        for (int i = tid; i < NB_C; i += 256)
            basep[i] = cur[i] ? atomicAdd(&bcnt[i], cur[i]) : 0;
        __syncthreads();

#pragma unroll
        for (int i = 0; i < PEPT; ++i) {
            if (bk[i] >= 0) {
                int pos = basep[bk[i]] + rk[i];
                if (pos < CAPB) edgesP[(size_t)bk[i] * CAPB + pos] = val[i];
            }
        }
    } else {
        // ---------------- GEMM role: yw = bf16(x W), no dinv ---------------
        unsigned short* sX = smem;             // swizzled x-tile; reused for C
        unsigned short* sW = smem + 128 * 128; // swizzled W^T
        long row0 = (long)pid * 128;

        // stage W: w[k*128+n] fp32 -> sW[swz(n,k)] bf16 (W^T, swizzled)
#pragma unroll
        for (int j = 0; j < 16; ++j) {
            int i4 = tid + j * 256;            // float4 index, 0..4095
            int i = i4 * 4;
            int k = i >> 7, n = i & 127;       // 4 consecutive n, same k
            floatx4 v = *(const floatx4*)(w + i);
            sW[swz(n + 0, k)] = f2b(v.x);
            sW[swz(n + 1, k)] = f2b(v.y);
            sW[swz(n + 2, k)] = f2b(v.z);
            sW[swz(n + 3, k)] = f2b(v.w);
        }
#pragma unroll
        for (int j = 0; j < 16; ++j) {
            int i = tid + j * 256;
            int r = i >> 5, q = i & 31;        // row r, 8 B chunk q (4 ushorts)
            floatx4 v = {0.f, 0.f, 0.f, 0.f};
            long gr = row0 + r;
            if (gr < NN) v = __builtin_nontemporal_load((const floatx4*)(x + gr * D + q * 4));
            ushort4 u;
            u.x = f2b(v.x); u.y = f2b(v.y); u.z = f2b(v.z); u.w = f2b(v.w);
            *(ushort4*)&sX[swz(r, q * 4)] = u;
        }
        __syncthreads();

        int lane = tid & 63, wave = tid >> 6;
        int wm = (wave & 1) * 64, wn = (wave >> 1) * 64;
        int lrow = lane & 15, lkb = (lane >> 4) * 8;

        floatx4 acc[4][4] = {};
#pragma unroll
        for (int kc = 0; kc < 4; ++kc) {
            int kb = kc * 32 + lkb;
            short8 bfr[4];
#pragma unroll
            for (int tn = 0; tn < 4; ++tn)
                bfr[tn] = *(const short8*)&sW[swz(wn + tn * 16 + lrow, kb)];
#pragma unroll
            for (int tm = 0; tm < 4; ++tm) {
                short8 afr = *(const short8*)&sX[swz(wm + tm * 16 + lrow, kb)];
#pragma unroll
                for (int tn = 0; tn < 4; ++tn)
                    acc[tm][tn] = __builtin_amdgcn_mfma_f32_16x16x32_bf16(afr, bfr[tn], acc[tm][tn], 0, 0, 0);
            }
        }

        // epilogue: stage C into sX (swizzled), flush row-major coalesced
        __syncthreads();
        int orow = (lane >> 4) * 4;
        int ocol = lane & 15;
#pragma unroll
        for (int tm = 0; tm < 4; ++tm) {
#pragma unroll
            for (int reg = 0; reg < 4; ++reg) {
                int rt = wm + tm * 16 + orow + reg;
#pragma unroll
                for (int tn = 0; tn < 4; ++tn)
                    sX[swz(rt, wn + tn * 16 + ocol)] = f2b(acc[tm][tn][reg]);
            }
        }
        __syncthreads();

#pragma unroll
        for (int j = 0; j < 8; ++j) {
            int i = tid + j * 256;
            int r = i >> 4, cg = i & 15;
            long gr = row0 + r;
            if (gr < NN) {
                uint4 v = *(const uint4*)&sX[swz(r, cg * 8)];
                *(uint4*)(yw + gr * D + cg * 8) = v;
            }
        }
    }
}

// ------------------------------------------ fine fill (1 block/bucket) ----
__global__ __launch_bounds__(1024) void k_fine(const int* __restrict__ bcnt,
                                               const unsigned int* __restrict__ edgesP,
                                               int* __restrict__ counts,
                                               float* __restrict__ dinv,
                                               int* __restrict__ srcs) {
    __shared__ int cnt[512];
    int t = threadIdx.x, b = blockIdx.x;
    int n0 = b << BSH;
    for (int i = t; i < 512; i += 1024) cnt[i] = 0;
    __syncthreads();

    int m = min(bcnt[b], CAPB);
    const unsigned int* ep = edgesP + (size_t)b * CAPB;
    for (int i = t; i < m; i += 1024) {
        unsigned int v = ep[i];
        int c0 = v >> 17;                     // dest & 511
        int s  = v & 0x1FFFF;                 // src
        int pos = atomicAdd(&cnt[c0], 1);     // LDS atomic
        if (pos < CAP) srcs[(size_t)(n0 + c0) * CAP + pos] = s;
    }
    __syncthreads();
    for (int i = t; i < 512; i += 1024) {
        int n = n0 + i;
        int cv = cnt[i];
        counts[n] = min(cv, CAP);
        dinv[n] = rsqrtf((float)cv + 1.0f);   // +1 appended self-loop (true degree)
    }
}

// --------------------------------------- per-node aggregate, wave/dest ----
// r5 champion structure + per-source dinv scale (moved out of gemm): lane
// group g owns source p+g (16 B row slice per lane); shfl broadcasts both
// the index and its dinv; adds become FMAs (same instr count -- r3 proved
// insensitivity). dinv is 400 KB -> gathers L2/L3-resident.
__global__ __launch_bounds__(256) void k_agg(const int* __restrict__ counts,
                                             const int* __restrict__ srcs,
                                             const float* __restrict__ dinv,
                                             const uintx4* __restrict__ yw4,
                                             const float* __restrict__ bias,
                                             float* __restrict__ out) {
    int lane = threadIdx.x & 63;
    int c = blockIdx.x * 4 + (threadIdx.x >> 6);
    int g = lane >> 4, f = lane & 15;

    // effective source list: [c (self), srcs[0..cnt0-1]], cnt0 capped at 63
    int cnt0 = min(counts[c], 63);
    const int* sp = srcs + (size_t)c * CAP;
    int mysrc = c;
    if (lane >= 1 && lane <= cnt0) mysrc = __builtin_nontemporal_load(sp + lane - 1);
    float myds = dinv[mysrc];                  // per-lane source scale
    int ec = cnt0 + 1;

    float dc = dinv[c];

    float a[8] = {0.f, 0.f, 0.f, 0.f, 0.f, 0.f, 0.f, 0.f};

    int p = 0;
    for (; p + 16 <= ec; p += 16) {
        uintx4 v[4]; float d[4];
#pragma unroll
        for (int i = 0; i < 4; ++i) {
            int ix = p + i * 4 + g;
            int s = __shfl(mysrc, ix);
            d[i] = __shfl(myds, ix);
            v[i] = yw4[(size_t)s * 16 + f];
        }
#pragma unroll
        for (int i = 0; i < 4; ++i) acc8f(a, v[i], d[i]);
    }
    if (p + 8 <= ec) {
        uintx4 v[2]; float d[2];
#pragma unroll
        for (int i = 0; i < 2; ++i) {
            int ix = p + i * 4 + g;
            int s = __shfl(mysrc, ix);
            d[i] = __shfl(myds, ix);
            v[i] = yw4[(size_t)s * 16 + f];
        }
#pragma unroll
        for (int i = 0; i < 2; ++i) acc8f(a, v[i], d[i]);
        p += 8;
    }
    if (p + 4 <= ec) {
        int s = __shfl(mysrc, p + g);
        float d = __shfl(myds, p + g);
        uintx4 v = yw4[(size_t)s * 16 + f];
        acc8f(a, v, d);
        p += 4;
    }
    int r = ec - p;                            // 0..3 remaining
    if (r > 0) {
        int ix = p + ((g < r) ? g : 0);
        int s = __shfl(mysrc, ix);
        float d = __shfl(myds, ix);
        uintx4 v = yw4[(size_t)s * 16 + f];
        if (g < r) acc8f(a, v, d);
    }

    // combine the 4 group-partials: lanes {f, f+16, f+32, f+48} -> full sum
#pragma unroll
    for (int j = 0; j < 8; ++j) a[j] += __shfl_xor(a[j], 16);
#pragma unroll
    for (int j = 0; j < 8; ++j) a[j] += __shfl_xor(a[j], 32);

    if (g == 0) {                              // lanes 0-15 store the row
        const floatx4* b4 = (const floatx4*)bias;
        floatx4 b0 = b4[f * 2], b1 = b4[f * 2 + 1];
        floatx4 o0, o1;
        o0.x = dc * a[0] + b0.x;  o0.y = dc * a[1] + b0.y;
        o0.z = dc * a[2] + b0.z;  o0.w = dc * a[3] + b0.w;
        o1.x = dc * a[4] + b1.x;  o1.y = dc * a[5] + b1.y;
        o1.z = dc * a[6] + b1.z;  o1.w = dc * a[7] + b1.w;
        floatx4* op = (floatx4*)(out + (size_t)c * D + f * 8);
        __builtin_nontemporal_store(o0, op);
        __builtin_nontemporal_store(o1, op + 1);
    }
}

// ---------------------------------------------------------------- launch ----
extern "C" void kernel_launch(void* const* d_in, const int* in_sizes, int n_in,
                              void* d_out, int out_size, void* d_ws, size_t ws_size,
                              hipStream_t stream) {
    const float* x    = (const float*)d_in[0];
    const int*   ei   = (const int*)d_in[1];      // [2, NE] (int32 on device)
    const float* w    = (const float*)d_in[2];
    const float* bias = (const float*)d_in[3];
    float*       out  = (float*)d_out;

    const int* row = ei;
    const int* col = ei + NE;

    // ws layout (~52 MB):
    int*   counts = (int*)d_ws;                          // NPAD
    float* dinv   = (float*)(counts + NPAD);             // NPAD
    int*   srcs   = (int*)(dinv + NPAD);                 // NN*CAP   (25.6 MB)
    unsigned short* yw = (unsigned short*)(srcs + (size_t)NN * CAP);  // NN*D bf16 (25.6 MB)
    int*   bcnt   = (int*)(yw + (size_t)NN * D);         // NB_C
    // edgesP (7.2 MB) aliases d_out: out is dead until k_agg writes it,
    // and yw is now LIVE during the fused kernel (can't alias it anymore).
    unsigned int* edgesP = (unsigned int*)d_out;

    hipMemsetAsync(bcnt, 0, NB_C * sizeof(int), stream);

    k_fused<<<FUSED_BLOCKS, 256, 0, stream>>>(x, w, row, col, bcnt, edgesP, yw);
    k_fine<<<NB_C, 1024, 0, stream>>>(bcnt, edgesP, counts, dinv, srcs);
    k_agg<<<NN / 4, 256, 0, stream>>>(counts, srcs, dinv, (const uintx4*)yw, bias, out);
}

// Round 12
// 232.526 us; speedup vs baseline: 1.0133x; 1.0133x over previous
//
#include <hip/hip_runtime.h>
#include <hip/hip_bf16.h>

#define NN 100000
#define NE 1600000
#define D  128
#define NPAD 100352           // 392 * 256 = 196 * 512
#define NBLK 782              // ceil(NN / 128)
#define CAP  64               // max in-degree bucket (Poisson(16): P(>=64)~8e-20)

// coarse partition params
#define BSH    9              // bucket = dest >> 9  (512 nodes/bucket)
#define NB_C   196            // NPAD >> 9
#define CAPB   9216           // bucket arena capacity (mean 8163, +11 sigma)
#define PCHUNK 2048           // edges per partition block (256 thr, proven r5 cfg)
#define PEPT   8              // edges per thread
#define NPART  782            // ceil(NE / PCHUNK)
#define FUSED_BLOCKS (NPART + NBLK)   // 1564: even = part, odd = gemm

typedef __attribute__((ext_vector_type(8))) short short8;
typedef __attribute__((ext_vector_type(4))) float floatx4;
typedef __attribute__((ext_vector_type(4))) unsigned int uintx4;

__device__ __forceinline__ unsigned short f2b(float f) {
    __hip_bfloat16 h = __float2bfloat16(f);   // RNE
    return *(unsigned short*)&h;
}

// scaled unpack-accumulate: a[j] += d * bf16_unpack(v)[j]  (8 FMAs)
__device__ __forceinline__ void acc8f(float (&a)[8], uintx4 v, float d) {
    a[0] += d * __uint_as_float(v.x << 16);
    a[1] += d * __uint_as_float(v.x & 0xFFFF0000u);
    a[2] += d * __uint_as_float(v.y << 16);
    a[3] += d * __uint_as_float(v.y & 0xFFFF0000u);
    a[4] += d * __uint_as_float(v.z << 16);
    a[5] += d * __uint_as_float(v.z & 0xFFFF0000u);
    a[6] += d * __uint_as_float(v.w << 16);
    a[7] += d * __uint_as_float(v.w & 0xFFFF0000u);
}

// LDS tile swizzle for [128 rows][128 bf16] (256 B rows): XOR 16 B-granule
// index with (row&7) -- G4 pattern. In ushort units: col ^ ((row&7)<<3).
__device__ __forceinline__ int swz(int row, int col_us) {
    return row * 128 + (col_us ^ ((row & 7) << 3));
}

// ------------------- FUSED: partition (even blocks) + GEMM (odd blocks) ----
// r12 fixes of r11's occupancy collapse (13%, 64 KB LDS) and W-stage bank
// conflicts (6.6M):
//  * LDS 64->32 KB: x is read exactly once per block, so sX staging was
//    pure overhead -- A-fragments now load straight from global (nt);
//    only W is staged (32 KB), and sW is reused for the C-tile.
//  * W-stage: thread covers (n, k..k+3): coalesced global reads, ONE 8 B
//    ushort4 LDS write; row-XOR swizzle spreads 8 n's across 8 bank-groups
//    (~2-way, free) instead of 16-way serialization.
__global__ __launch_bounds__(256, 4) void k_fused(const float* __restrict__ x,
                                                  const float* __restrict__ w,
                                                  const int* __restrict__ row,
                                                  const int* __restrict__ col,
                                                  int* __restrict__ bcnt,
                                                  unsigned int* __restrict__ edgesP,
                                                  unsigned short* __restrict__ yw) {
    __shared__ __align__(16) unsigned short sW[128 * 128];   // 32 KB; W^T then C
    int tid = threadIdx.x;
    int pid = blockIdx.x >> 1;

    if ((blockIdx.x & 1) == 0) {
        // ---------------- partition role (r5-proven 2048@256 shape) --------
        int* cur   = (int*)sW;
        int* basep = cur + NB_C;
        size_t e0 = (size_t)pid * PCHUNK;

        for (int i = tid; i < NB_C; i += 256) cur[i] = 0;
        __syncthreads();

        unsigned int val[PEPT];
        int bk[PEPT], rk[PEPT];
#pragma unroll
        for (int i = 0; i < PEPT; ++i) {
            size_t e = e0 + i * 256 + tid;
            bk[i] = -1;
            if (e < NE) {
                int r = row[e], c = col[e];
                if (r != c) {                  // existing self-loops weight 0
                    bk[i]  = c >> BSH;
                    val[i] = (unsigned)r | ((unsigned)(c & 511) << 17);
                    rk[i]  = atomicAdd(&cur[bk[i]], 1);   // LDS atomic
                }
            }
        }
        __syncthreads();

        for (int i = tid; i < NB_C; i += 256)
            basep[i] = cur[i] ? atomicAdd(&bcnt[i], cur[i]) : 0;
        __syncthreads();

#pragma unroll
        for (int i = 0; i < PEPT; ++i) {
            if (bk[i] >= 0) {
                int pos = basep[bk[i]] + rk[i];
                if (pos < CAPB) edgesP[(size_t)bk[i] * CAPB + pos] = val[i];
            }
        }
    } else {
        // ---------------- GEMM role: yw = bf16(x W), no dinv ---------------
        long row0 = (long)pid * 128;

        // stage W conflict-free: thread -> (n, 4 consecutive k), ushort4 write
#pragma unroll
        for (int j = 0; j < 16; ++j) {
            int idx = tid + j * 256;           // 0..4095
            int n = idx & 127, k = (idx >> 7) * 4;
            ushort4 u;
            u.x = f2b(w[(k + 0) * D + n]);
            u.y = f2b(w[(k + 1) * D + n]);
            u.z = f2b(w[(k + 2) * D + n]);
            u.w = f2b(w[(k + 3) * D + n]);
            *(ushort4*)&sW[swz(n, k)] = u;
        }
        __syncthreads();

        int lane = tid & 63, wave = tid >> 6;
        int wm = (wave & 1) * 64, wn = (wave >> 1) * 64;
        int lrow = lane & 15, lkb = (lane >> 4) * 8;

        floatx4 acc[4][4] = {};
#pragma unroll
        for (int kc = 0; kc < 4; ++kc) {
            int kb = kc * 32 + lkb;
            short8 bfr[4];
#pragma unroll
            for (int tn = 0; tn < 4; ++tn)
                bfr[tn] = *(const short8*)&sW[swz(wn + tn * 16 + lrow, kb)];
#pragma unroll
            for (int tm = 0; tm < 4; ++tm) {
                int rt = wm + tm * 16 + lrow;
                long gr = row0 + rt;
                short8 afr = {0, 0, 0, 0, 0, 0, 0, 0};
                if (gr < NN) {                 // A-frag direct from global (nt)
                    floatx4 v0 = __builtin_nontemporal_load((const floatx4*)(x + gr * D + kb));
                    floatx4 v1 = __builtin_nontemporal_load((const floatx4*)(x + gr * D + kb + 4));
                    afr[0] = (short)f2b(v0.x); afr[1] = (short)f2b(v0.y);
                    afr[2] = (short)f2b(v0.z); afr[3] = (short)f2b(v0.w);
                    afr[4] = (short)f2b(v1.x); afr[5] = (short)f2b(v1.y);
                    afr[6] = (short)f2b(v1.z); afr[7] = (short)f2b(v1.w);
                }
#pragma unroll
                for (int tn = 0; tn < 4; ++tn)
                    acc[tm][tn] = __builtin_amdgcn_mfma_f32_16x16x32_bf16(afr, bfr[tn], acc[tm][tn], 0, 0, 0);
            }
        }

        // epilogue: sW is dead -> stage C there (swizzled), flush coalesced
        __syncthreads();
        int orow = (lane >> 4) * 4;
        int ocol = lane & 15;
#pragma unroll
        for (int tm = 0; tm < 4; ++tm) {
#pragma unroll
            for (int reg = 0; reg < 4; ++reg) {
                int rt = wm + tm * 16 + orow + reg;
#pragma unroll
                for (int tn = 0; tn < 4; ++tn)
                    sW[swz(rt, wn + tn * 16 + ocol)] = f2b(acc[tm][tn][reg]);
            }
        }
        __syncthreads();

#pragma unroll
        for (int j = 0; j < 8; ++j) {
            int i = tid + j * 256;
            int r = i >> 4, cg = i & 15;
            long gr = row0 + r;
            if (gr < NN) {
                uint4 v = *(const uint4*)&sW[swz(r, cg * 8)];
                *(uint4*)(yw + gr * D + cg * 8) = v;
            }
        }
    }
}

// ------------------------------------------ fine fill (1 block/bucket) ----
__global__ __launch_bounds__(1024) void k_fine(const int* __restrict__ bcnt,
                                               const unsigned int* __restrict__ edgesP,
                                               int* __restrict__ counts,
                                               float* __restrict__ dinv,
                                               int* __restrict__ srcs) {
    __shared__ int cnt[512];
    int t = threadIdx.x, b = blockIdx.x;
    int n0 = b << BSH;
    for (int i = t; i < 512; i += 1024) cnt[i] = 0;
    __syncthreads();

    int m = min(bcnt[b], CAPB);
    const unsigned int* ep = edgesP + (size_t)b * CAPB;
    for (int i = t; i < m; i += 1024) {
        unsigned int v = ep[i];
        int c0 = v >> 17;                     // dest & 511
        int s  = v & 0x1FFFF;                 // src
        int pos = atomicAdd(&cnt[c0], 1);     // LDS atomic
        if (pos < CAP) srcs[(size_t)(n0 + c0) * CAP + pos] = s;
    }
    __syncthreads();
    for (int i = t; i < 512; i += 1024) {
        int n = n0 + i;
        int cv = cnt[i];
        counts[n] = min(cv, CAP);
        dinv[n] = rsqrtf((float)cv + 1.0f);   // +1 appended self-loop (true degree)
    }
}

// --------------------------------------- per-node aggregate, wave/dest ----
// r5 champion structure + per-source dinv scale (moved out of gemm so the
// gemm is edge-independent and fusable): lane group g owns source p+g
// (16 B row slice per lane); shfl broadcasts index + dinv; FMA accumulate.
__global__ __launch_bounds__(256) void k_agg(const int* __restrict__ counts,
                                             const int* __restrict__ srcs,
                                             const float* __restrict__ dinv,
                                             const uintx4* __restrict__ yw4,
                                             const float* __restrict__ bias,
                                             float* __restrict__ out) {
    int lane = threadIdx.x & 63;
    int c = blockIdx.x * 4 + (threadIdx.x >> 6);
    int g = lane >> 4, f = lane & 15;

    // effective source list: [c (self), srcs[0..cnt0-1]], cnt0 capped at 63
    int cnt0 = min(counts[c], 63);
    const int* sp = srcs + (size_t)c * CAP;
    int mysrc = c;
    if (lane >= 1 && lane <= cnt0) mysrc = __builtin_nontemporal_load(sp + lane - 1);
    float myds = dinv[mysrc];                  // per-lane source scale
    int ec = cnt0 + 1;

    float dc = dinv[c];

    float a[8] = {0.f, 0.f, 0.f, 0.f, 0.f, 0.f, 0.f, 0.f};

    int p = 0;
    for (; p + 16 <= ec; p += 16) {
        uintx4 v[4]; float d[4];
#pragma unroll
        for (int i = 0; i < 4; ++i) {
            int ix = p + i * 4 + g;
            int s = __shfl(mysrc, ix);
            d[i] = __shfl(myds, ix);
            v[i] = yw4[(size_t)s * 16 + f];
        }
#pragma unroll
        for (int i = 0; i < 4; ++i) acc8f(a, v[i], d[i]);
    }
    if (p + 8 <= ec) {
        uintx4 v[2]; float d[2];
#pragma unroll
        for (int i = 0; i < 2; ++i) {
            int ix = p + i * 4 + g;
            int s = __shfl(mysrc, ix);
            d[i] = __shfl(myds, ix);
            v[i] = yw4[(size_t)s * 16 + f];
        }
#pragma unroll
        for (int i = 0; i < 2; ++i) acc8f(a, v[i], d[i]);
        p += 8;
    }
    if (p + 4 <= ec) {
        int s = __shfl(mysrc, p + g);
        float d = __shfl(myds, p + g);
        uintx4 v = yw4[(size_t)s * 16 + f];
        acc8f(a, v, d);
        p += 4;
    }
    int r = ec - p;                            // 0..3 remaining
    if (r > 0) {
        int ix = p + ((g < r) ? g : 0);
        int s = __shfl(mysrc, ix);
        float d = __shfl(myds, ix);
        uintx4 v = yw4[(size_t)s * 16 + f];
        if (g < r) acc8f(a, v, d);
    }

    // combine the 4 group-partials: lanes {f, f+16, f+32, f+48} -> full sum
#pragma unroll
    for (int j = 0; j < 8; ++j) a[j] += __shfl_xor(a[j], 16);
#pragma unroll
    for (int j = 0; j < 8; ++j) a[j] += __shfl_xor(a[j], 32);

    if (g == 0) {                              // lanes 0-15 store the row
        const floatx4* b4 = (const floatx4*)bias;
        floatx4 b0 = b4[f * 2], b1 = b4[f * 2 + 1];
        floatx4 o0, o1;
        o0.x = dc * a[0] + b0.x;  o0.y = dc * a[1] + b0.y;
        o0.z = dc * a[2] + b0.z;  o0.w = dc * a[3] + b0.w;
        o1.x = dc * a[4] + b1.x;  o1.y = dc * a[5] + b1.y;
        o1.z = dc * a[6] + b1.z;  o1.w = dc * a[7] + b1.w;
        floatx4* op = (floatx4*)(out + (size_t)c * D + f * 8);
        __builtin_nontemporal_store(o0, op);
        __builtin_nontemporal_store(o1, op + 1);
    }
}

// ---------------------------------------------------------------- launch ----
extern "C" void kernel_launch(void* const* d_in, const int* in_sizes, int n_in,
                              void* d_out, int out_size, void* d_ws, size_t ws_size,
                              hipStream_t stream) {
    const float* x    = (const float*)d_in[0];
    const int*   ei   = (const int*)d_in[1];      // [2, NE] (int32 on device)
    const float* w    = (const float*)d_in[2];
    const float* bias = (const float*)d_in[3];
    float*       out  = (float*)d_out;

    const int* row = ei;
    const int* col = ei + NE;

    // ws layout (~52 MB):
    int*   counts = (int*)d_ws;                          // NPAD
    float* dinv   = (float*)(counts + NPAD);             // NPAD
    int*   srcs   = (int*)(dinv + NPAD);                 // NN*CAP   (25.6 MB)
    unsigned short* yw = (unsigned short*)(srcs + (size_t)NN * CAP);  // NN*D bf16 (25.6 MB)
    int*   bcnt   = (int*)(yw + (size_t)NN * D);         // NB_C
    // edgesP (7.2 MB) aliases d_out: out is dead until k_agg writes it,
    // and yw is LIVE during the fused kernel (can't alias it).
    unsigned int* edgesP = (unsigned int*)d_out;

    hipMemsetAsync(bcnt, 0, NB_C * sizeof(int), stream);

    k_fused<<<FUSED_BLOCKS, 256, 0, stream>>>(x, w, row, col, bcnt, edgesP, yw);
    k_fine<<<NB_C, 1024, 0, stream>>>(bcnt, edgesP, counts, dinv, srcs);
    k_agg<<<NN / 4, 256, 0, stream>>>(counts, srcs, dinv, (const uintx4*)yw, bias, out);
}